// Round 1
// baseline (3757.309 us; speedup 1.0000x reference)
//
#include <hip/hip_runtime.h>
#include <math.h>

constexpr int B = 8, C = 64, H = 256, W = 256, HWc = H * W, N = 10;

// ---------------- LayerNorm over channel dim (per pixel) ----------------
__global__ __launch_bounds__(256) void ln_kernel(
    const float* __restrict__ x, const float* __restrict__ g,
    const float* __restrict__ bta, float* __restrict__ xn) {
  int pix = blockIdx.x * 256 + threadIdx.x;  // 0..HW-1
  int b = blockIdx.y;
  const float* xp = x + (size_t)b * C * HWc + pix;
  float s = 0.f, s2 = 0.f;
#pragma unroll
  for (int c = 0; c < C; c++) {
    float v = xp[(size_t)c * HWc];
    s += v; s2 += v * v;
  }
  float mu = s * (1.f / C);
  float var = s2 * (1.f / C) - mu * mu;
  float rstd = rsqrtf(var + 1e-5f);
  float* op = xn + (size_t)b * C * HWc + pix;
#pragma unroll
  for (int c = 0; c < C; c++) {
    float v = xp[(size_t)c * HWc];
    op[(size_t)c * HWc] = (v - mu) * rstd * g[c] + bta[c];
  }
}

// ---------------- direct 3x3 conv, 4px x 4co register tile ----------------
// ACT: 0=none, 1=exact gelu. RES: add residual (same layout as out).
template <int ACT, bool RES>
__global__ __launch_bounds__(256) void conv3x3_k(
    const float* __restrict__ in, const float* __restrict__ wgt,
    const float* __restrict__ bias, const float* __restrict__ resid,
    float* __restrict__ out) {
  __shared__ float ws[4 * 64 * 9];  // 4 co x 64 ci x 9 taps
  int tid = threadIdx.x;
  int cog = blockIdx.y;  // 0..15
  for (int i = tid; i < 4 * 64 * 9; i += 256) ws[i] = wgt[cog * (4 * 64 * 9) + i];
  __syncthreads();

  int b = blockIdx.z;
  int ty = tid >> 6;   // 0..3 (row within tile)
  int tx = tid & 63;   // 0..63 (w segment of 4)
  int h = blockIdx.x * 4 + ty;
  int w0 = tx * 4;

  float acc[4][4];
#pragma unroll
  for (int q = 0; q < 4; q++) {
    float bv = bias[cog * 4 + q];
#pragma unroll
    for (int p = 0; p < 4; p++) acc[q][p] = bv;
  }

  const float* inb = in + (size_t)b * C * HWc;
  for (int ci = 0; ci < C; ci++) {
    float r[3][6];
    const float* pc = inb + (size_t)ci * HWc;
#pragma unroll
    for (int dy = 0; dy < 3; dy++) {
      int hh = h + dy - 1;
      if (hh < 0 || hh >= H) {
#pragma unroll
        for (int dx = 0; dx < 6; dx++) r[dy][dx] = 0.f;
      } else {
        const float* row = pc + hh * W;
#pragma unroll
        for (int dx = 0; dx < 6; dx++) {
          int ww = w0 + dx - 1;
          r[dy][dx] = (ww >= 0 && ww < W) ? row[ww] : 0.f;
        }
      }
    }
#pragma unroll
    for (int q = 0; q < 4; q++) {
      const float* wq = &ws[(q * 64 + ci) * 9];
#pragma unroll
      for (int dy = 0; dy < 3; dy++)
#pragma unroll
        for (int dx = 0; dx < 3; dx++) {
          float wv = wq[dy * 3 + dx];
#pragma unroll
          for (int p = 0; p < 4; p++) acc[q][p] += r[dy][dx + p] * wv;
        }
    }
  }

#pragma unroll
  for (int q = 0; q < 4; q++) {
    int co = cog * 4 + q;
    size_t base_o = ((size_t)b * C + co) * HWc + (size_t)h * W + w0;
#pragma unroll
    for (int p = 0; p < 4; p++) {
      float v = acc[q][p];
      if (ACT == 1) v = 0.5f * v * (1.f + erff(v * 0.70710678118654752f));
      if (RES) v += resid[base_o + p];
      out[base_o + p] = v;
    }
  }
}

// ---------------- depthwise 3x3 conv + global-average-pool partial ----------------
__global__ __launch_bounds__(256) void dwgap_k(
    const float* __restrict__ x1, const float* __restrict__ dww,
    float* __restrict__ pooled) {
  int c = blockIdx.y, b = blockIdx.z;
  int pix = blockIdx.x * 256 + threadIdx.x;
  int h = pix >> 8, w = pix & 255;
  const float* p = x1 + ((size_t)b * C + c) * HWc;
  float wv[9];
#pragma unroll
  for (int t = 0; t < 9; t++) wv[t] = dww[c * 9 + t];
  float s = 0.f;
#pragma unroll
  for (int dy = 0; dy < 3; dy++) {
    int hh = h + dy - 1;
    if (hh < 0 || hh >= H) continue;
#pragma unroll
    for (int dx = 0; dx < 3; dx++) {
      int ww = w + dx - 1;
      if (ww < 0 || ww >= W) continue;
      s += p[hh * W + ww] * wv[dy * 3 + dx];
    }
  }
  __shared__ float red[256];
  red[threadIdx.x] = s;
  __syncthreads();
  for (int off = 128; off > 0; off >>= 1) {
    if (threadIdx.x < off) red[threadIdx.x] += red[threadIdx.x + off];
    __syncthreads();
  }
  if (threadIdx.x == 0) atomicAdd(&pooled[b * C + c], red[0]);
}

// ---------------- MLP + softmax + basis blend ----------------
__global__ void mlp_k(const float* __restrict__ pooled, const float* __restrict__ dwb,
                      const float* __restrict__ c1w, const float* __restrict__ c1b,
                      const float* __restrict__ c2w, const float* __restrict__ c2b,
                      const float* __restrict__ basep, float* __restrict__ Wm) {
  int b = blockIdx.x;
  int t = threadIdx.x;  // 64 threads
  __shared__ float pm[64], p1[64], p2[16];
  pm[t] = pooled[b * 64 + t] * (1.f / HWc) + dwb[t];
  __syncthreads();
  float a = c1b[t];
  for (int ci = 0; ci < 64; ci++) a += pm[ci] * c1w[t * 64 + ci];
  p1[t] = fmaxf(a, 0.f);
  __syncthreads();
  if (t < N) {
    float a2 = c2b[t];
    for (int ci = 0; ci < 64; ci++) a2 += p1[ci] * c2w[t * 64 + ci];
    p2[t] = a2;
  }
  __syncthreads();
  // softmax (redundant per-thread)
  float m = -1e30f;
  for (int n = 0; n < N; n++) m = fmaxf(m, p2[n]);
  float e[N], s = 0.f;
  for (int n = 0; n < N; n++) { e[n] = expf(p2[n] - m); s += e[n]; }
  float inv = 1.f / s;
  // Wm[b][k][l] = sum_n w[n] * base[n][k][l]; 4096 entries over 64 threads
  for (int j = 0; j < 64; j++) {
    int idx = j * 64 + t;
    float acc = 0.f;
    for (int n = 0; n < N; n++) acc += e[n] * inv * basep[n * 4096 + idx];
    Wm[b * 4096 + idx] = acc;
  }
}

// ---------------- per-pixel channel mix: out[l] = sum_k Wm[k][l]*xm[k] ----------------
__global__ __launch_bounds__(256) void mix_k(
    const float* __restrict__ xm, const float* __restrict__ Wm,
    float* __restrict__ xm2) {
  int b = blockIdx.y;
  int pix = blockIdx.x * 256 + threadIdx.x;
  __shared__ float Ws[4096];
  for (int i = threadIdx.x; i < 4096; i += 256) Ws[i] = Wm[b * 4096 + i];
  __syncthreads();
  const float* xp = xm + (size_t)b * 64 * HWc + pix;
  float acc[64];
#pragma unroll
  for (int l = 0; l < 64; l++) acc[l] = 0.f;
  for (int k = 0; k < 64; k++) {
    float v = xp[(size_t)k * HWc];
    const float* wrow = &Ws[k * 64];  // einsum bkl,bkm->blm: sum over k (first idx)
#pragma unroll
    for (int l = 0; l < 64; l++) acc[l] += v * wrow[l];
  }
  float* op = xm2 + (size_t)b * 64 * HWc + pix;
#pragma unroll
  for (int l = 0; l < 64; l++) op[(size_t)l * HWc] = acc[l];
}

__global__ void zero_k(float* p, int n) {
  int i = blockIdx.x * 256 + threadIdx.x;
  if (i < n) p[i] = 0.f;
}

extern "C" void kernel_launch(void* const* d_in, const int* in_sizes, int n_in,
                              void* d_out, int out_size, void* d_ws, size_t ws_size,
                              hipStream_t stream) {
  const float* x       = (const float*)d_in[0];
  const float* ln_g    = (const float*)d_in[1];
  const float* ln_b    = (const float*)d_in[2];
  const float* conv3_w = (const float*)d_in[3];
  const float* conv3_b = (const float*)d_in[4];
  const float* dw_w    = (const float*)d_in[5];
  const float* dw_b    = (const float*)d_in[6];
  const float* c1_w    = (const float*)d_in[7];
  const float* c1_b    = (const float*)d_in[8];
  const float* c2_w    = (const float*)d_in[9];
  const float* c2_b    = (const float*)d_in[10];
  const float* basep   = (const float*)d_in[11];
  const float* up_w    = (const float*)d_in[12];
  const float* up_b    = (const float*)d_in[13];
  const float* down_w  = (const float*)d_in[14];
  const float* down_b  = (const float*)d_in[15];
  float* out = (float*)d_out;

  char* wsb = (char*)d_ws;
  size_t big = (size_t)B * C * HWc * sizeof(float);  // 134,217,728 bytes
  float* bufA   = (float*)wsb;                        // xn, later xm
  float* bufB   = (float*)(wsb + big);                // x1, later xm2
  float* pooled = (float*)(wsb + 2 * big);            // [B*C]
  float* Wm     = (float*)(wsb + 2 * big + 2048);     // [B*64*64]

  // 1. LayerNorm: x -> bufA
  ln_kernel<<<dim3(HWc / 256, B), 256, 0, stream>>>(x, ln_g, ln_b, bufA);
  // zero pooled accumulator (must re-zero every call)
  zero_k<<<2, 256, 0, stream>>>(pooled, B * C);
  // 2. conv3 + gelu: bufA -> bufB (x1)
  conv3x3_k<1, false><<<dim3(H / 4, C / 4, B), 256, 0, stream>>>(
      bufA, conv3_w, conv3_b, nullptr, bufB);
  // 3. dwconv + GAP: bufB -> pooled
  dwgap_k<<<dim3(HWc / 256, C, B), 256, 0, stream>>>(bufB, dw_w, pooled);
  // 4. MLP + softmax + blend: pooled -> Wm
  mlp_k<<<B, 64, 0, stream>>>(pooled, dw_b, c1_w, c1_b, c2_w, c2_b, basep, Wm);
  // 5. up conv: bufB -> bufA (xm)
  conv3x3_k<0, false><<<dim3(H / 4, C / 4, B), 256, 0, stream>>>(
      bufB, up_w, up_b, nullptr, bufA);
  // 6. channel mix: bufA -> bufB (xm2)
  mix_k<<<dim3(HWc / 256, B), 256, 0, stream>>>(bufA, Wm, bufB);
  // 7. down conv + residual: bufB -> out
  conv3x3_k<0, true><<<dim3(H / 4, C / 4, B), 256, 0, stream>>>(
      bufB, down_w, down_b, x, out);
}

// Round 2
// 464.740 us; speedup vs baseline: 8.0847x; 8.0847x over previous
//
#include <hip/hip_runtime.h>
#include <math.h>

constexpr int B = 8, C = 64, H = 256, W = 256, HWc = H * W, N = 10;

typedef short bf8 __attribute__((ext_vector_type(8)));    // 8 x bf16 (4 VGPR)
typedef float f4  __attribute__((ext_vector_type(4)));    // MFMA accum
typedef unsigned short ushort;

__device__ __forceinline__ ushort f2bf(float f) {
  unsigned u = __builtin_bit_cast(unsigned, f);
  unsigned r = (u + 0x7fffu + ((u >> 16) & 1u)) >> 16;
  return (ushort)r;
}
__device__ __forceinline__ float bf2f(ushort h) {
  unsigned u = ((unsigned)h) << 16;
  return __builtin_bit_cast(float, u);
}

// ---------------- LayerNorm: NCHW fp32 -> NHWC bf16 ----------------
__global__ __launch_bounds__(256) void ln_k(
    const float* __restrict__ x, const float* __restrict__ g,
    const float* __restrict__ bt, ushort* __restrict__ xn) {
  int pix = blockIdx.x * 256 + threadIdx.x;
  int b = blockIdx.y;
  const float* xp = x + (size_t)b * C * HWc + pix;
  float v[64];
  float s = 0.f, s2 = 0.f;
#pragma unroll
  for (int c = 0; c < 64; c++) {
    v[c] = xp[(size_t)c * HWc];
    s += v[c]; s2 += v[c] * v[c];
  }
  float mu = s * (1.f / 64);
  float var = s2 * (1.f / 64) - mu * mu;
  float rstd = rsqrtf(var + 1e-5f);
  ushort* op = xn + ((size_t)b * HWc + pix) * 64;
#pragma unroll
  for (int ch = 0; ch < 8; ch++) {
    union { ushort us[8]; int4 v4; } pk;
#pragma unroll
    for (int j = 0; j < 8; j++) {
      int c = ch * 8 + j;
      pk.us[j] = f2bf((v[c] - mu) * rstd * g[c] + bt[c]);
    }
    *reinterpret_cast<int4*>(op + ch * 8) = pk.v4;
  }
}

// ---------------- weight prep: OIHW fp32 -> MFMA fragment layout bf16 ----------------
// frag element: frags[conv][((s*4+cf)*64+lane)*8+j] = w[co][ci][tap]
//   co = cf*16 + (lane&15); tap = s>>1; ci = (s&1)*32 + (lane>>4)*8 + j
__global__ void prep_w(const float* __restrict__ w3, const float* __restrict__ wu,
                       const float* __restrict__ wd, ushort* __restrict__ frags) {
  int idx = blockIdx.x * 256 + threadIdx.x;
  if (idx >= 3 * 4608) return;
  int conv = idx / 4608, r = idx % 4608;
  int s = r >> 8, cf = (r >> 6) & 3, lane = r & 63;
  const float* w = (conv == 0) ? w3 : (conv == 1) ? wu : wd;
  int co = (cf << 4) + (lane & 15);
  int tap = s >> 1;
  ushort* o = frags + conv * 36864 + ((size_t)r) * 8;
#pragma unroll
  for (int j = 0; j < 8; j++) {
    int ci = ((s & 1) << 5) + ((lane >> 4) << 3) + j;
    o[j] = f2bf(w[(co * 64 + ci) * 9 + tap]);
  }
}

// ---------------- MFMA implicit-GEMM 3x3 conv ----------------
// in: NHWC bf16. OM=0: out NHWC bf16. OM=1: out NCHW fp32 + residual (NCHW fp32).
// ACT=1: exact GELU.
template <int ACT, int OM>
__global__ __launch_bounds__(256) void conv_mfma(
    const ushort* __restrict__ in, const ushort* __restrict__ wfrag,
    const float* __restrict__ bias, const float* __restrict__ resid,
    ushort* __restrict__ outb, float* __restrict__ outf) {
  __shared__ char lds[18 * 18 * 128];  // 41472 B, swizzled
  int tid = threadIdx.x;
  int b = blockIdx.z;
  int h0 = blockIdx.y * 16, w0 = blockIdx.x * 16;

  // stage 18x18 pixel tile (halo), 8 chunks of 8 ci each, XOR swizzle on col
  for (int idx = tid; idx < 18 * 18 * 8; idx += 256) {
    int pix = idx >> 3, ch = idx & 7;
    int r = pix / 18, c = pix % 18;
    int gh = h0 + r - 1, gw = w0 + c - 1;
    int4 v = make_int4(0, 0, 0, 0);
    if (gh >= 0 && gh < H && gw >= 0 && gw < W)
      v = *reinterpret_cast<const int4*>(in + (((size_t)b * H + gh) * W + gw) * 64 + ch * 8);
    int off = ((pix << 7) + (ch << 4)) ^ ((c & 7) << 4);
    *reinterpret_cast<int4*>(lds + off) = v;
  }
  __syncthreads();

  int wave = tid >> 6, lane = tid & 63;
  int lm = lane & 15, lk = lane >> 4;  // col-of-frag / k-group

  f4 acc[4][4];
#pragma unroll
  for (int cf = 0; cf < 4; cf++) {
    float bv = bias[(cf << 4) + lm];
    f4 ini = {bv, bv, bv, bv};
#pragma unroll
    for (int f = 0; f < 4; f++) acc[f][cf] = ini;
  }

  const bf8* wf = reinterpret_cast<const bf8*>(wfrag);
#pragma unroll
  for (int s = 0; s < 18; s++) {
    int tap = s >> 1;
    int dy = tap / 3, dx = tap % 3;
    int kbyte = (((s & 1) << 5) + (lk << 3)) << 1;  // ci0*2 bytes, in {0,16,...,112}
    bf8 a[4], bb[4];
#pragma unroll
    for (int f = 0; f < 4; f++) {
      int lr = (wave << 2) + f + dy;
      int lc = lm + dx;
      int off = (((lr * 18 + lc) << 7) + kbyte) ^ ((lc & 7) << 4);
      a[f] = *reinterpret_cast<const bf8*>(lds + off);
    }
#pragma unroll
    for (int cf = 0; cf < 4; cf++) bb[cf] = wf[(s << 2) + cf ? ((s * 4 + cf) * 64 + lane) : ((s * 4) * 64 + lane)];
#pragma unroll
    for (int cf = 0; cf < 4; cf++) bb[cf] = wf[((s * 4 + cf) * 64 + lane)];
#pragma unroll
    for (int f = 0; f < 4; f++)
#pragma unroll
      for (int cf = 0; cf < 4; cf++)
        acc[f][cf] = __builtin_amdgcn_mfma_f32_16x16x32_bf16(a[f], bb[cf], acc[f][cf], 0, 0, 0);
  }

  // epilogue: D layout col(co)=lane&15, row(pixel-in-row)=(lane>>4)*4+reg
#pragma unroll
  for (int f = 0; f < 4; f++) {
    int h = h0 + (wave << 2) + f;
#pragma unroll
    for (int cf = 0; cf < 4; cf++) {
      int co = (cf << 4) + lm;
      if (OM == 0) {
#pragma unroll
        for (int r = 0; r < 4; r++) {
          int wc = w0 + (lk << 2) + r;
          float v = acc[f][cf][r];
          if (ACT) v = 0.5f * v * (1.f + erff(v * 0.70710678118654752f));
          outb[(((size_t)b * H + h) * W + wc) * 64 + co] = f2bf(v);
        }
      } else {
        int wc0 = w0 + (lk << 2);
        size_t o = ((size_t)(b * 64 + co)) * HWc + (size_t)h * W + wc0;
        float4 rv = *reinterpret_cast<const float4*>(resid + o);
        float4 ov;
        ov.x = acc[f][cf][0] + rv.x;
        ov.y = acc[f][cf][1] + rv.y;
        ov.z = acc[f][cf][2] + rv.z;
        ov.w = acc[f][cf][3] + rv.w;
        *reinterpret_cast<float4*>(outf + o) = ov;
      }
    }
  }
}

// ---------------- depthwise 3x3 + GAP (NHWC bf16 in) ----------------
__global__ __launch_bounds__(256) void dwgap_k(
    const ushort* __restrict__ x1, const float* __restrict__ dww,
    float* __restrict__ pooled) {
  int c = threadIdx.x & 63;
  int q = threadIdx.x >> 6;
  int seg = blockIdx.x * 4 + q;  // 0..1023
  int row = seg >> 2;
  int wbase = (seg & 3) * 64;
  int b = blockIdx.y;
  float wv[9];
#pragma unroll
  for (int t = 0; t < 9; t++) wv[t] = dww[c * 9 + t];

  auto ld = [&](int hh, int ww) -> float {
    if (hh < 0 || hh >= H || ww < 0 || ww >= W) return 0.f;
    return bf2f(x1[(((size_t)b * H + hh) * W + ww) * 64 + c]);
  };
  float v[3][3];
#pragma unroll
  for (int dy = 0; dy < 3; dy++) {
    v[dy][0] = ld(row + dy - 1, wbase - 1);
    v[dy][1] = ld(row + dy - 1, wbase);
  }
  float acc = 0.f;
  for (int i = 0; i < 64; i++) {
    int w = wbase + i;
#pragma unroll
    for (int dy = 0; dy < 3; dy++) v[dy][2] = ld(row + dy - 1, w + 1);
    float s = 0.f;
#pragma unroll
    for (int dy = 0; dy < 3; dy++)
#pragma unroll
      for (int dx = 0; dx < 3; dx++) s += v[dy][dx] * wv[dy * 3 + dx];
    acc += s;
#pragma unroll
    for (int dy = 0; dy < 3; dy++) { v[dy][0] = v[dy][1]; v[dy][1] = v[dy][2]; }
  }
  atomicAdd(&pooled[b * 64 + c], acc);
}

// ---------------- MLP + softmax + blend -> Wm in B-fragment layout ----------------
__global__ void mlp_k(const float* __restrict__ pooled, const float* __restrict__ dwb,
                      const float* __restrict__ c1w, const float* __restrict__ c1b,
                      const float* __restrict__ c2w, const float* __restrict__ c2b,
                      const float* __restrict__ basep, ushort* __restrict__ wmf) {
  int b = blockIdx.x;
  int t = threadIdx.x;  // 64 threads
  __shared__ float pm[64], p1[64], p2[16];
  pm[t] = pooled[b * 64 + t] * (1.f / HWc) + dwb[t];
  __syncthreads();
  float a = c1b[t];
  for (int ci = 0; ci < 64; ci++) a += pm[ci] * c1w[t * 64 + ci];
  p1[t] = fmaxf(a, 0.f);
  __syncthreads();
  if (t < N) {
    float a2 = c2b[t];
    for (int ci = 0; ci < 64; ci++) a2 += p1[ci] * c2w[t * 64 + ci];
    p2[t] = a2;
  }
  __syncthreads();
  float m = -1e30f;
  for (int n = 0; n < N; n++) m = fmaxf(m, p2[n]);
  float e[N], s = 0.f;
  for (int n = 0; n < N; n++) { e[n] = expf(p2[n] - m); s += e[n]; }
  float inv = 1.f / s;
  // wmf[b][(s2*4+cf)*64+lane][j] = Wm[k][l], k = s2*32+(lane>>4)*8+j, l = cf*16+(lane&15)
  for (int idx = t; idx < 4096; idx += 64) {
    int j = idx & 7, lane = (idx >> 3) & 63, cf = (idx >> 9) & 3, s2 = idx >> 11;
    int k = (s2 << 5) + ((lane >> 4) << 3) + j;
    int l = (cf << 4) + (lane & 15);
    float acc = 0.f;
    for (int n = 0; n < N; n++) acc += e[n] * inv * basep[n * 4096 + k * 64 + l];
    wmf[(size_t)b * 4096 + idx] = f2bf(acc);
  }
}

// ---------------- per-pixel 64x64 channel mix via MFMA ----------------
__global__ __launch_bounds__(256) void mix_mfma(
    const ushort* __restrict__ xm, const ushort* __restrict__ wmf,
    ushort* __restrict__ out) {
  __shared__ char lds[16 * 16 * 128];  // 32 KB
  int tid = threadIdx.x;
  int b = blockIdx.z;
  int h0 = blockIdx.y * 16, w0 = blockIdx.x * 16;
  for (int idx = tid; idx < 16 * 16 * 8; idx += 256) {
    int pix = idx >> 3, ch = idx & 7;
    int r = pix >> 4, c = pix & 15;
    int4 v = *reinterpret_cast<const int4*>(xm + (((size_t)b * H + h0 + r) * W + w0 + c) * 64 + ch * 8);
    int off = ((pix << 7) + (ch << 4)) ^ ((c & 7) << 4);
    *reinterpret_cast<int4*>(lds + off) = v;
  }
  __syncthreads();
  int wave = tid >> 6, lane = tid & 63;
  int lm = lane & 15, lk = lane >> 4;
  f4 acc[4][4];
#pragma unroll
  for (int f = 0; f < 4; f++)
#pragma unroll
    for (int cf = 0; cf < 4; cf++) acc[f][cf] = (f4){0.f, 0.f, 0.f, 0.f};
  const bf8* wf = reinterpret_cast<const bf8*>(wmf + (size_t)b * 4096);
#pragma unroll
  for (int s = 0; s < 2; s++) {
    int kbyte = ((s << 5) + (lk << 3)) << 1;
    bf8 a[4], bb[4];
#pragma unroll
    for (int f = 0; f < 4; f++) {
      int lr = (wave << 2) + f;
      int off = ((((lr << 4) + lm) << 7) + kbyte) ^ ((lm & 7) << 4);
      a[f] = *reinterpret_cast<const bf8*>(lds + off);
    }
#pragma unroll
    for (int cf = 0; cf < 4; cf++) bb[cf] = wf[(s << 2) + cf];
    // note: B-frag per lane: wf[((s*4+cf)*64+lane)]
#pragma unroll
    for (int cf = 0; cf < 4; cf++) bb[cf] = wf[((s * 4 + cf) * 64 + lane)];
#pragma unroll
    for (int f = 0; f < 4; f++)
#pragma unroll
      for (int cf = 0; cf < 4; cf++)
        acc[f][cf] = __builtin_amdgcn_mfma_f32_16x16x32_bf16(a[f], bb[cf], acc[f][cf], 0, 0, 0);
  }
#pragma unroll
  for (int f = 0; f < 4; f++) {
    int h = h0 + (wave << 2) + f;
#pragma unroll
    for (int cf = 0; cf < 4; cf++) {
      int co = (cf << 4) + lm;
#pragma unroll
      for (int r = 0; r < 4; r++) {
        int wc = w0 + (lk << 2) + r;
        out[(((size_t)b * H + h) * W + wc) * 64 + co] = f2bf(acc[f][cf][r]);
      }
    }
  }
}

__global__ void zero_k(float* p, int n) {
  int i = blockIdx.x * 256 + threadIdx.x;
  if (i < n) p[i] = 0.f;
}

extern "C" void kernel_launch(void* const* d_in, const int* in_sizes, int n_in,
                              void* d_out, int out_size, void* d_ws, size_t ws_size,
                              hipStream_t stream) {
  const float* x       = (const float*)d_in[0];
  const float* ln_g    = (const float*)d_in[1];
  const float* ln_b    = (const float*)d_in[2];
  const float* conv3_w = (const float*)d_in[3];
  const float* conv3_b = (const float*)d_in[4];
  const float* dw_w    = (const float*)d_in[5];
  const float* dw_b    = (const float*)d_in[6];
  const float* c1_w    = (const float*)d_in[7];
  const float* c1_b    = (const float*)d_in[8];
  const float* c2_w    = (const float*)d_in[9];
  const float* c2_b    = (const float*)d_in[10];
  const float* basep   = (const float*)d_in[11];
  const float* up_w    = (const float*)d_in[12];
  const float* up_b    = (const float*)d_in[13];
  const float* down_w  = (const float*)d_in[14];
  const float* down_b  = (const float*)d_in[15];
  float* out = (float*)d_out;

  char* wsb = (char*)d_ws;
  size_t big = (size_t)B * HWc * 64 * sizeof(ushort);  // 67,108,864
  ushort* bufA   = (ushort*)wsb;
  ushort* bufB   = (ushort*)(wsb + big);
  ushort* wfrags = (ushort*)(wsb + 2 * big);                    // 3 x 36864
  ushort* wmfrag = (ushort*)(wsb + 2 * big + 3 * 36864 * 2);    // 8 x 4096
  float*  pooled = (float*)(wsb + 2 * big + 3 * 36864 * 2 + 8 * 4096 * 2);

  prep_w<<<54, 256, 0, stream>>>(conv3_w, up_w, down_w, wfrags);
  zero_k<<<2, 256, 0, stream>>>(pooled, B * C);
  // 1. LN: x -> bufA (NHWC bf16)
  ln_k<<<dim3(HWc / 256, B), 256, 0, stream>>>(x, ln_g, ln_b, bufA);
  // 2. conv3 + GELU: bufA -> bufB
  conv_mfma<1, 0><<<dim3(16, 16, B), 256, 0, stream>>>(
      bufA, wfrags + 0 * 36864, conv3_b, nullptr, bufB, nullptr);
  // 3. dw + GAP: bufB -> pooled
  dwgap_k<<<dim3(256, B), 256, 0, stream>>>(bufB, dw_w, pooled);
  // 4. MLP + blend: pooled -> wmfrag
  mlp_k<<<B, 64, 0, stream>>>(pooled, dw_b, c1_w, c1_b, c2_w, c2_b, basep, wmfrag);
  // 5. up conv: bufB -> bufA (xm)
  conv_mfma<0, 0><<<dim3(16, 16, B), 256, 0, stream>>>(
      bufB, wfrags + 1 * 36864, up_b, nullptr, bufA, nullptr);
  // 6. mix: bufA -> bufB (xm2)
  mix_mfma<<<dim3(16, 16, B), 256, 0, stream>>>(bufA, wmfrag, bufB);
  // 7. down conv + residual: bufB -> out (NCHW fp32)
  conv_mfma<0, 1><<<dim3(16, 16, B), 256, 0, stream>>>(
      bufB, wfrags + 2 * 36864, down_b, x, nullptr, out);
}